// Round 1
// baseline (390.810 us; speedup 1.0000x reference)
//
#include <hip/hip_runtime.h>

// PSROIPool direct-summation kernel.
// Semantics exactly mirror the reference:
//   rnd(v) = floor(v+0.5); start/end scaled by SPATIAL_SCALE=1/16
//   roi_w/h = max(end-start, 0.1); bin = roi/7
//   hs = clip(floor(ph*bin_h + roi_sh), 0, H); he = clip(ceil((ph+1)*bin_h + roi_sh), 0, H)
//   c  = (d*7 + ph)*7 + pw
//   out = area>0 ? sum(region)/area : 0
// Direct sum over [hs,he)x[ws,we) == SAT 4-corner difference (exact arithmetic),
// and has LESS f32 rounding error than the SAT approach.

#define PSB 4
#define PSC 1029
#define PSH 80
#define PSW 80
#define PSD 21            // 1029 / 49
#define PSCALE 0.0625f

__global__ __launch_bounds__(256) void psroi_pool_kernel(
    const float* __restrict__ x,     // [B, C, H, W]
    const float* __restrict__ rois,  // [N, 5]
    float* __restrict__ out,         // [N, D, 7, 7]
    int total)
{
    int idx = blockIdx.x * blockDim.x + threadIdx.x;
    if (idx >= total) return;

    int pw = idx % 7;
    int ph = (idx / 7) % 7;
    int d  = (idx / 49) % PSD;
    int n  = idx / (49 * PSD);

    const float* r = rois + (size_t)n * 5;
    int   b      = (int)r[0];
    float roi_sw = floorf(r[1] + 0.5f) * PSCALE;
    float roi_sh = floorf(r[2] + 0.5f) * PSCALE;
    float roi_ew = floorf(r[3] + 1.5f) * PSCALE;   // rnd(x2 + 1.0)
    float roi_eh = floorf(r[4] + 1.5f) * PSCALE;

    float roi_w = fmaxf(roi_ew - roi_sw, 0.1f);
    float roi_h = fmaxf(roi_eh - roi_sh, 0.1f);
    float bin_h = roi_h * (1.0f / 7.0f);
    float bin_w = roi_w * (1.0f / 7.0f);

    int hs = (int)fminf(fmaxf(floorf((float)ph * bin_h + roi_sh), 0.0f), (float)PSH);
    int he = (int)fminf(fmaxf(ceilf(((float)ph + 1.0f) * bin_h + roi_sh), 0.0f), (float)PSH);
    int ws = (int)fminf(fmaxf(floorf((float)pw * bin_w + roi_sw), 0.0f), (float)PSW);
    int we = (int)fminf(fmaxf(ceilf(((float)pw + 1.0f) * bin_w + roi_sw), 0.0f), (float)PSW);

    int c = (d * 7 + ph) * 7 + pw;
    const float* plane = x + ((size_t)b * PSC + c) * (PSH * PSW);

    float s = 0.0f;
    for (int h = hs; h < he; ++h) {
        const float* row = plane + h * PSW;
        for (int w = ws; w < we; ++w) {
            s += row[w];
        }
    }

    int area = (he - hs) * (we - ws);
    out[idx] = (area > 0) ? s / (float)area : 0.0f;
}

extern "C" void kernel_launch(void* const* d_in, const int* in_sizes, int n_in,
                              void* d_out, int out_size, void* d_ws, size_t ws_size,
                              hipStream_t stream) {
    const float* x    = (const float*)d_in[0];
    const float* rois = (const float*)d_in[1];
    float* out        = (float*)d_out;

    int total = out_size;  // 1024 * 21 * 7 * 7 = 1,053,696
    int block = 256;
    int grid  = (total + block - 1) / block;
    psroi_pool_kernel<<<grid, block, 0, stream>>>(x, rois, out, total);
}

// Round 2
// 202.063 us; speedup vs baseline: 1.9341x; 1.9341x over previous
//
#include <hip/hip_runtime.h>

// PSROIPool, plane-resident formulation.
// One block per (b, c) feature-map plane. The plane (80x80 f32 = 25.6 KB) is
// staged into LDS with coalesced float4 loads (input read exactly once,
// 105 MB total). Each plane corresponds to a single (d, ph, pw) output bin
// position; threads then sweep the roi list, select rois whose batch == b,
// and compute that bin's region-average from LDS.
//
// Rounding semantics exactly mirror the reference (verified R1, absmax 7.8e-3):
//   rnd(v)=floor(v+0.5); scale=1/16; roi_w/h = max(end-start, 0.1); bin=roi/7
//   hs=clip(floor(ph*bin_h+roi_sh),0,80); he=clip(ceil((ph+1)*bin_h+roi_sh),0,80)

#define PSB 4
#define PSC 1029
#define PSH 80
#define PSW 80
#define PSD 21
#define PSCALE 0.0625f
#define PLANE_ELEMS (PSH * PSW)   // 6400

__global__ __launch_bounds__(256) void psroi_plane_kernel(
    const float* __restrict__ x,     // [B, C, H, W]
    const float* __restrict__ rois,  // [N, 5]
    float* __restrict__ out,         // [N, D, 7, 7] == [N, C]
    int N)
{
    const int blk = blockIdx.x;          // 0 .. B*C-1
    const int b   = blk / PSC;
    const int c   = blk - b * PSC;
    const int d   = c / 49;
    const int ph  = (c / 7) % 7;
    const int pw  = c % 7;

    __shared__ float plane[PLANE_ELEMS];

    // Stage plane (b, c) into LDS: 1600 float4 loads across 256 threads.
    {
        const float4* __restrict__ src4 =
            (const float4*)(x + ((size_t)b * PSC + c) * PLANE_ELEMS);
        float4* dst4 = (float4*)plane;
        #pragma unroll
        for (int i = 0; i < PLANE_ELEMS / 4 / 256 + 1; ++i) {
            int j = threadIdx.x + i * 256;
            if (j < PLANE_ELEMS / 4) dst4[j] = src4[j];
        }
    }
    __syncthreads();

    const float fph = (float)ph, fpw = (float)pw;

    for (int n = threadIdx.x; n < N; n += 256) {
        const float* __restrict__ r = rois + (size_t)n * 5;
        int rb = (int)r[0];
        if (rb != b) continue;

        float roi_sw = floorf(r[1] + 0.5f) * PSCALE;
        float roi_sh = floorf(r[2] + 0.5f) * PSCALE;
        float roi_ew = floorf(r[3] + 1.5f) * PSCALE;   // rnd(x2 + 1.0)
        float roi_eh = floorf(r[4] + 1.5f) * PSCALE;

        float roi_w = fmaxf(roi_ew - roi_sw, 0.1f);
        float roi_h = fmaxf(roi_eh - roi_sh, 0.1f);
        float bin_h = roi_h * (1.0f / 7.0f);
        float bin_w = roi_w * (1.0f / 7.0f);

        int hs = (int)fminf(fmaxf(floorf(fph * bin_h + roi_sh), 0.0f), (float)PSH);
        int he = (int)fminf(fmaxf(ceilf((fph + 1.0f) * bin_h + roi_sh), 0.0f), (float)PSH);
        int ws = (int)fminf(fmaxf(floorf(fpw * bin_w + roi_sw), 0.0f), (float)PSW);
        int we = (int)fminf(fmaxf(ceilf((fpw + 1.0f) * bin_w + roi_sw), 0.0f), (float)PSW);

        float s = 0.0f;
        for (int h = hs; h < he; ++h) {
            const float* row = plane + h * PSW;
            for (int w = ws; w < we; ++w) s += row[w];
        }

        int area = (he - hs) * (we - ws);
        // out index: ((n*D + d)*7 + ph)*7 + pw  ==  n*C + c
        out[(size_t)n * PSC + c] = (area > 0) ? s / (float)area : 0.0f;
    }
}

extern "C" void kernel_launch(void* const* d_in, const int* in_sizes, int n_in,
                              void* d_out, int out_size, void* d_ws, size_t ws_size,
                              hipStream_t stream) {
    const float* x    = (const float*)d_in[0];
    const float* rois = (const float*)d_in[1];
    float* out        = (float*)d_out;
    int N = in_sizes[1] / 5;   // 1024

    psroi_plane_kernel<<<PSB * PSC, 256, 0, stream>>>(x, rois, out, N);
}

// Round 3
// 175.005 us; speedup vs baseline: 2.2331x; 1.1546x over previous
//
#include <hip/hip_runtime.h>
#include <stdint.h>

// PSROIPool, plane-resident + precomputed-geometry formulation.
//
// Kernel 1 (prep): per roi, precompute the 7 h-ranges (hs|he<<8 as u16) and
// 7 w-ranges, and bucket roi indices by batch (atomics). Geometry computed
// once per roi instead of once per (roi, plane).
//
// Kernel 2 (main): one block per (b,c) plane. Plane staged to LDS via
// global_load_lds width=16 (async, no VGPR round-trip). Threads then sweep
// only the rois of batch b (1 roi/thread), each: 2 u16 table loads + direct
// region sum from LDS.
//
// Rounding semantics mirror the reference exactly (verified R1/R2,
// absmax 7.8e-3 vs threshold 8.1e-2).

#define PSB 4
#define PSC 1029
#define PSH 80
#define PSW 80
#define PSCALE 0.0625f
#define PLANE_ELEMS (PSH * PSW)   // 6400
#define NROI_MAX 1024

// workspace layout (bytes):
//   0     : int counts[4]
//   16    : int lists[4][1024]
//   16400 : u16 hTab[1024*7]   (hs | he<<8)
//   30736 : u16 wTab[1024*7]   (ws | we<<8)
#define WS_COUNTS 0
#define WS_LISTS  16
#define WS_HTAB   (16 + 4 * NROI_MAX * 4)
#define WS_WTAB   (WS_HTAB + NROI_MAX * 7 * 2)

typedef __attribute__((address_space(3))) void lds_void;
typedef __attribute__((address_space(1))) void glob_void;

__global__ __launch_bounds__(256) void psroi_prep_kernel(
    const float* __restrict__ rois, int N,
    int* __restrict__ counts, int* __restrict__ lists,
    uint16_t* __restrict__ hTab, uint16_t* __restrict__ wTab)
{
    int n = blockIdx.x * blockDim.x + threadIdx.x;
    if (n >= N) return;

    const float* r = rois + (size_t)n * 5;
    int   b      = (int)r[0];
    float roi_sw = floorf(r[1] + 0.5f) * PSCALE;
    float roi_sh = floorf(r[2] + 0.5f) * PSCALE;
    float roi_ew = floorf(r[3] + 1.5f) * PSCALE;   // rnd(x2 + 1.0)
    float roi_eh = floorf(r[4] + 1.5f) * PSCALE;

    float roi_w = fmaxf(roi_ew - roi_sw, 0.1f);
    float roi_h = fmaxf(roi_eh - roi_sh, 0.1f);
    float bin_h = roi_h * (1.0f / 7.0f);
    float bin_w = roi_w * (1.0f / 7.0f);

    #pragma unroll
    for (int p = 0; p < 7; ++p) {
        float fp = (float)p;
        int hs = (int)fminf(fmaxf(floorf(fp * bin_h + roi_sh), 0.0f), (float)PSH);
        int he = (int)fminf(fmaxf(ceilf((fp + 1.0f) * bin_h + roi_sh), 0.0f), (float)PSH);
        int ws = (int)fminf(fmaxf(floorf(fp * bin_w + roi_sw), 0.0f), (float)PSW);
        int we = (int)fminf(fmaxf(ceilf((fp + 1.0f) * bin_w + roi_sw), 0.0f), (float)PSW);
        hTab[n * 7 + p] = (uint16_t)(hs | (he << 8));
        wTab[n * 7 + p] = (uint16_t)(ws | (we << 8));
    }

    int slot = atomicAdd(&counts[b], 1);
    lists[b * NROI_MAX + slot] = n;
}

__global__ __launch_bounds__(256) void psroi_main_kernel(
    const float* __restrict__ x,          // [B, C, H, W]
    float* __restrict__ out,              // [N, C]
    const int* __restrict__ counts,
    const int* __restrict__ lists,
    const uint16_t* __restrict__ hTab,
    const uint16_t* __restrict__ wTab)
{
    const int blk = blockIdx.x;           // 0 .. B*C-1
    const int b   = blk / PSC;
    const int c   = blk - b * PSC;
    const int ph  = (c / 7) % 7;
    const int pw  = c % 7;

    __shared__ float plane[PLANE_ELEMS];

    // Async stage plane (b,c): 1600 x 16B via global_load_lds (linear LDS dest).
    {
        const float4* src4 = (const float4*)(x + ((size_t)b * PSC + c) * PLANE_ELEMS);
        float4* dst4 = (float4*)plane;
        int tid = threadIdx.x;
        #pragma unroll
        for (int i = 0; i < 6; ++i) {
            __builtin_amdgcn_global_load_lds(
                (const glob_void*)(src4 + tid + i * 256),
                (lds_void*)(dst4 + tid + i * 256), 16, 0, 0);
        }
        if (tid < 64) {   // wave-uniform branch (wave 0 only)
            __builtin_amdgcn_global_load_lds(
                (const glob_void*)(src4 + tid + 1536),
                (lds_void*)(dst4 + tid + 1536), 16, 0, 0);
        }
    }
    __syncthreads();   // drains vmcnt + barrier

    const int cnt = counts[b];
    const int* list = lists + b * NROI_MAX;

    for (int i = threadIdx.x; i < cnt; i += 256) {
        int n  = list[i];
        int hr = hTab[n * 7 + ph];
        int wr = wTab[n * 7 + pw];
        int hs = hr & 0xFF, he = hr >> 8;
        int ws = wr & 0xFF, we = wr >> 8;

        float s = 0.0f;
        for (int h = hs; h < he; ++h) {
            const float* row = plane + h * PSW;
            for (int w = ws; w < we; ++w) s += row[w];
        }

        int area = (he - hs) * (we - ws);
        out[(size_t)n * PSC + c] = (area > 0) ? s / (float)area : 0.0f;
    }
}

extern "C" void kernel_launch(void* const* d_in, const int* in_sizes, int n_in,
                              void* d_out, int out_size, void* d_ws, size_t ws_size,
                              hipStream_t stream) {
    const float* x    = (const float*)d_in[0];
    const float* rois = (const float*)d_in[1];
    float* out        = (float*)d_out;
    int N = in_sizes[1] / 5;   // 1024

    char* ws = (char*)d_ws;
    int*      counts = (int*)(ws + WS_COUNTS);
    int*      lists  = (int*)(ws + WS_LISTS);
    uint16_t* hTab   = (uint16_t*)(ws + WS_HTAB);
    uint16_t* wTab   = (uint16_t*)(ws + WS_WTAB);

    hipMemsetAsync(counts, 0, 4 * sizeof(int), stream);
    psroi_prep_kernel<<<(N + 255) / 256, 256, 0, stream>>>(
        rois, N, counts, lists, hTab, wTab);
    psroi_main_kernel<<<PSB * PSC, 256, 0, stream>>>(
        x, out, counts, lists, hTab, wTab);
}

// Round 4
// 171.751 us; speedup vs baseline: 2.2754x; 1.0189x over previous
//
#include <hip/hip_runtime.h>
#include <stdint.h>

// PSROIPool: plane-resident + size-sorted roi slots + transposed output.
//
// prep   : 1 block x 1024 threads. Per roi: geometry tables (u16 packed
//          ranges per ph / pw). Counting sort by (batch, quantized bin size)
//          via LDS histogram + scan -> slot order groups similar-sized rois,
//          so the main kernel's wave-divergent sum loop runs ~mean instead of
//          ~max iterations.
// main   : one block per (b,c) plane; plane (25.6 KB) staged to LDS via
//          global_load_lds w=16. Threads sweep batch-b slot range, direct
//          region sum from LDS, write outT[c][slot] (coalesced).
// transp : 32x32 LDS tile transpose outT[C][1024] -> out[N][C] via list[slot].
//
// Rounding semantics mirror the reference exactly (verified R1-R3, absmax 7.8e-3).

#define PSB 4
#define PSC 1029
#define PSH 80
#define PSW 80
#define PSCALE 0.0625f
#define PLANE_ELEMS (PSH * PSW)   // 6400
#define NMAX 1024
#define NCLASS 32
#define NKEYS (PSB * NCLASS)      // 128

// workspace layout (bytes)
#define WS_OFF  0                       // int off[8]
#define WS_LIST 32                      // int list[NMAX]
#define WS_HTAB (WS_LIST + NMAX * 4)    // u16 hTab[NMAX*7]
#define WS_WTAB (WS_HTAB + NMAX * 7 * 2)
#define WS_OUTT 65536                   // float outT[PSC * NMAX] (~4.2 MB)

typedef __attribute__((address_space(3))) void lds_void;
typedef __attribute__((address_space(1))) void glob_void;

__global__ __launch_bounds__(1024) void psroi_prep(
    const float* __restrict__ rois, int N,
    int* __restrict__ off_g, int* __restrict__ list,
    uint16_t* __restrict__ hTab, uint16_t* __restrict__ wTab)
{
    __shared__ int hist[NKEYS];
    __shared__ int scan[NKEYS];
    __shared__ int cur[NKEYS];

    const int tid = threadIdx.x;
    if (tid < NKEYS) hist[tid] = 0;
    __syncthreads();

    const bool act = tid < N;
    int key = 0;
    uint16_t hr[7], wr[7];

    if (act) {
        const float* r = rois + (size_t)tid * 5;
        int   b      = (int)r[0];
        float roi_sw = floorf(r[1] + 0.5f) * PSCALE;
        float roi_sh = floorf(r[2] + 0.5f) * PSCALE;
        float roi_ew = floorf(r[3] + 1.5f) * PSCALE;   // rnd(x2 + 1.0)
        float roi_eh = floorf(r[4] + 1.5f) * PSCALE;

        float roi_w = fmaxf(roi_ew - roi_sw, 0.1f);
        float roi_h = fmaxf(roi_eh - roi_sh, 0.1f);
        float bin_h = roi_h * (1.0f / 7.0f);
        float bin_w = roi_w * (1.0f / 7.0f);

        #pragma unroll
        for (int p = 0; p < 7; ++p) {
            float fp = (float)p;
            int hs = (int)fminf(fmaxf(floorf(fp * bin_h + roi_sh), 0.0f), (float)PSH);
            int he = (int)fminf(fmaxf(ceilf((fp + 1.0f) * bin_h + roi_sh), 0.0f), (float)PSH);
            int ws = (int)fminf(fmaxf(floorf(fp * bin_w + roi_sw), 0.0f), (float)PSW);
            int we = (int)fminf(fmaxf(ceilf((fp + 1.0f) * bin_w + roi_sw), 0.0f), (float)PSW);
            hr[p] = (uint16_t)(hs | (he << 8));
            wr[p] = (uint16_t)(ws | (we << 8));
        }

        int kh = min(7, (int)bin_h);
        int kw = min(3, (int)(bin_w * 0.75f));
        key = b * NCLASS + kh * 4 + kw;
        atomicAdd(&hist[key], 1);
    }
    __syncthreads();

    // inclusive Hillis-Steele scan of hist -> scan
    if (tid < NKEYS) scan[tid] = hist[tid];
    __syncthreads();
    for (int o = 1; o < NKEYS; o <<= 1) {
        int t = 0;
        if (tid < NKEYS && tid >= o) t = scan[tid - o];
        __syncthreads();
        if (tid < NKEYS) scan[tid] += t;
        __syncthreads();
    }

    if (tid < NKEYS) cur[tid] = scan[tid] - hist[tid];   // exclusive offset
    if (tid < PSB)   off_g[tid] = scan[tid * NCLASS] - hist[tid * NCLASS];
    if (tid == 0)    off_g[PSB] = N;
    __syncthreads();

    if (act) {
        int slot = atomicAdd(&cur[key], 1);
        list[slot] = tid;
        #pragma unroll
        for (int p = 0; p < 7; ++p) {
            hTab[slot * 7 + p] = hr[p];
            wTab[slot * 7 + p] = wr[p];
        }
    }
}

__global__ __launch_bounds__(256) void psroi_main(
    const float* __restrict__ x,          // [B, C, H, W]
    float* __restrict__ outT,             // [C, NMAX]
    const int* __restrict__ off_g,        // [5]
    const uint16_t* __restrict__ hTab,
    const uint16_t* __restrict__ wTab)
{
    const int blk = blockIdx.x;           // 0 .. B*C-1
    const int b   = blk / PSC;
    const int c   = blk - b * PSC;
    const int ph  = (c / 7) % 7;
    const int pw  = c % 7;

    __shared__ float plane[PLANE_ELEMS];

    {
        const float4* src4 = (const float4*)(x + ((size_t)b * PSC + c) * PLANE_ELEMS);
        float4* dst4 = (float4*)plane;
        int tid = threadIdx.x;
        #pragma unroll
        for (int i = 0; i < 6; ++i) {
            __builtin_amdgcn_global_load_lds(
                (const glob_void*)(src4 + tid + i * 256),
                (lds_void*)(dst4 + tid + i * 256), 16, 0, 0);
        }
        if (tid < 64) {
            __builtin_amdgcn_global_load_lds(
                (const glob_void*)(src4 + tid + 1536),
                (lds_void*)(dst4 + tid + 1536), 16, 0, 0);
        }
    }
    __syncthreads();

    const int s0 = off_g[b];
    const int s1 = off_g[b + 1];

    for (int i = s0 + (int)threadIdx.x; i < s1; i += 256) {
        int hr = hTab[i * 7 + ph];
        int wr = wTab[i * 7 + pw];
        int hs = hr & 0xFF, he = hr >> 8;
        int ws = wr & 0xFF, we = wr >> 8;

        float s = 0.0f;
        for (int h = hs; h < he; ++h) {
            const float* row = plane + h * PSW;
            for (int w = ws; w < we; ++w) s += row[w];
        }

        int area = (he - hs) * (we - ws);
        outT[(size_t)c * NMAX + i] = (area > 0) ? s / (float)area : 0.0f;
    }
}

__global__ __launch_bounds__(256) void psroi_transpose(
    const float* __restrict__ outT,       // [C, NMAX]
    const int* __restrict__ list,         // slot -> n
    float* __restrict__ out)              // [N, C]
{
    __shared__ float tile[32][33];
    __shared__ int ntab[32];

    const int c0 = blockIdx.x * 32;
    const int s0 = blockIdx.y * 32;
    const int tid = threadIdx.x;

    if (tid < 32) ntab[tid] = list[s0 + tid];

    #pragma unroll
    for (int k = 0; k < 4; ++k) {
        int idx = tid + k * 256;
        int r = idx >> 5, s = idx & 31;
        int c = c0 + r;
        if (c < PSC) tile[r][s] = outT[(size_t)c * NMAX + s0 + s];
    }
    __syncthreads();

    #pragma unroll
    for (int k = 0; k < 4; ++k) {
        int idx = tid + k * 256;
        int j = idx >> 5, cc = idx & 31;
        int c = c0 + cc;
        if (c < PSC) out[(size_t)ntab[j] * PSC + c] = tile[cc][j];
    }
}

extern "C" void kernel_launch(void* const* d_in, const int* in_sizes, int n_in,
                              void* d_out, int out_size, void* d_ws, size_t ws_size,
                              hipStream_t stream) {
    const float* x    = (const float*)d_in[0];
    const float* rois = (const float*)d_in[1];
    float* out        = (float*)d_out;
    int N = in_sizes[1] / 5;   // 1024

    char* ws = (char*)d_ws;
    int*      off_g = (int*)(ws + WS_OFF);
    int*      list  = (int*)(ws + WS_LIST);
    uint16_t* hTab  = (uint16_t*)(ws + WS_HTAB);
    uint16_t* wTab  = (uint16_t*)(ws + WS_WTAB);
    float*    outT  = (float*)(ws + WS_OUTT);

    psroi_prep<<<1, 1024, 0, stream>>>(rois, N, off_g, list, hTab, wTab);
    psroi_main<<<PSB * PSC, 256, 0, stream>>>(x, outT, off_g, hTab, wTab);
    psroi_transpose<<<dim3((PSC + 31) / 32, N / 32), 256, 0, stream>>>(
        outT, list, out);
}

// Round 8
// 166.064 us; speedup vs baseline: 2.3534x; 1.0342x over previous
//
#include <hip/hip_runtime.h>
#include <stdint.h>

// PSROIPool: plane-resident + fine size-sorted slots + masked-float4 row dot.
//
// prep   : 1 block x 1024 threads. Per roi: u16 geometry tables. Counting
//          sort by key=(batch, ceil(bin_h) 0..7, ceil(bin_w) 0..7) -> 256
//          classes; wave lanes get near-identical h/w spans (divergence ~0).
// main   : one block per (b,c) plane; plane (25.6 KB) staged via
//          global_load_lds w=16; roi metadata prefetched into registers
//          BEFORE the stage barrier (latency hidden under the stage).
//          Region sum = per-row ds_read_b128 x (1..4) dotted with 0/1 masks
//          (no inner w-loop, no per-element bookkeeping).
//          Coalesced write to outT[c][slot].
// transp : 32x32 LDS tile transpose outT[C][1024] -> out[N][C] via list[slot].
//
// Rounding semantics mirror the reference exactly (verified R1-R4, absmax 7.8e-3).

#define PSB 4
#define PSC 1029
#define PSH 80
#define PSW 80
#define PSCALE 0.0625f
#define PLANE_ELEMS (PSH * PSW)   // 6400
#define NMAX 1024
#define NKEYS 256                 // 4 batches x 8 hclass x 8 wclass

// workspace layout (bytes)
#define WS_OFF  0                       // int off[8]
#define WS_LIST 32                      // int list[NMAX]
#define WS_HTAB (WS_LIST + NMAX * 4)    // u16 hTab[NMAX*7]
#define WS_WTAB (WS_HTAB + NMAX * 7 * 2)
#define WS_OUTT 65536                   // float outT[PSC * NMAX] (~4.2 MB)

typedef __attribute__((address_space(3))) void lds_void;
typedef __attribute__((address_space(1))) void glob_void;

__global__ __launch_bounds__(1024) void psroi_prep(
    const float* __restrict__ rois, int N,
    int* __restrict__ off_g, int* __restrict__ list,
    uint16_t* __restrict__ hTab, uint16_t* __restrict__ wTab)
{
    __shared__ int hist[NKEYS];
    __shared__ int scan[NKEYS];
    __shared__ int cur[NKEYS];

    const int tid = threadIdx.x;
    if (tid < NKEYS) hist[tid] = 0;
    __syncthreads();

    const bool act = tid < N;
    int key = 0;
    uint16_t hr[7], wr[7];

    if (act) {
        const float* r = rois + (size_t)tid * 5;
        int   b      = (int)r[0];
        float roi_sw = floorf(r[1] + 0.5f) * PSCALE;
        float roi_sh = floorf(r[2] + 0.5f) * PSCALE;
        float roi_ew = floorf(r[3] + 1.5f) * PSCALE;   // rnd(x2 + 1.0)
        float roi_eh = floorf(r[4] + 1.5f) * PSCALE;

        float roi_w = fmaxf(roi_ew - roi_sw, 0.1f);
        float roi_h = fmaxf(roi_eh - roi_sh, 0.1f);
        float bin_h = roi_h * (1.0f / 7.0f);
        float bin_w = roi_w * (1.0f / 7.0f);

        #pragma unroll
        for (int p = 0; p < 7; ++p) {
            float fp = (float)p;
            int hs = (int)fminf(fmaxf(floorf(fp * bin_h + roi_sh), 0.0f), (float)PSH);
            int he = (int)fminf(fmaxf(ceilf((fp + 1.0f) * bin_h + roi_sh), 0.0f), (float)PSH);
            int ws = (int)fminf(fmaxf(floorf(fp * bin_w + roi_sw), 0.0f), (float)PSW);
            int we = (int)fminf(fmaxf(ceilf((fp + 1.0f) * bin_w + roi_sw), 0.0f), (float)PSW);
            hr[p] = (uint16_t)(hs | (he << 8));
            wr[p] = (uint16_t)(ws | (we << 8));
        }

        int kh = min(7, (int)ceilf(bin_h));
        int kw = min(7, (int)ceilf(bin_w));
        key = b * 64 + kh * 8 + kw;
        atomicAdd(&hist[key], 1);
    }
    __syncthreads();

    if (tid < NKEYS) scan[tid] = hist[tid];
    __syncthreads();
    #pragma unroll
    for (int o = 1; o < NKEYS; o <<= 1) {
        int t = 0;
        if (tid < NKEYS && tid >= o) t = scan[tid - o];
        __syncthreads();
        if (tid < NKEYS) scan[tid] += t;
        __syncthreads();
    }

    if (tid < NKEYS) cur[tid] = scan[tid] - hist[tid];   // exclusive offsets
    if (tid < PSB)   off_g[tid] = scan[tid * 64] - hist[tid * 64];
    if (tid == 0)    off_g[PSB] = N;
    __syncthreads();

    if (act) {
        int slot = atomicAdd(&cur[key], 1);
        list[slot] = tid;
        #pragma unroll
        for (int p = 0; p < 7; ++p) {
            hTab[slot * 7 + p] = hr[p];
            wTab[slot * 7 + p] = wr[p];
        }
    }
}

__global__ __launch_bounds__(256) void psroi_main(
    const float* __restrict__ x,          // [B, C, H, W]
    float* __restrict__ outT,             // [C, NMAX]
    const int* __restrict__ off_g,        // [5]
    const uint16_t* __restrict__ hTab,
    const uint16_t* __restrict__ wTab)
{
    const int blk = blockIdx.x;           // 0 .. B*C-1
    const int b   = blk / PSC;
    const int c   = blk - b * PSC;
    const int ph  = (c / 7) % 7;
    const int pw  = c % 7;

    __shared__ float plane[PLANE_ELEMS];

    // Issue async stage first (25 x 1KB global_load_lds wave-ops).
    {
        const float4* src4 = (const float4*)(x + ((size_t)b * PSC + c) * PLANE_ELEMS);
        float4* dst4 = (float4*)plane;
        int tid = threadIdx.x;
        #pragma unroll
        for (int i = 0; i < 6; ++i) {
            __builtin_amdgcn_global_load_lds(
                (const glob_void*)(src4 + tid + i * 256),
                (lds_void*)(dst4 + tid + i * 256), 16, 0, 0);
        }
        if (tid < 64) {
            __builtin_amdgcn_global_load_lds(
                (const glob_void*)(src4 + tid + 1536),
                (lds_void*)(dst4 + tid + 1536), 16, 0, 0);
        }
    }

    // Prefetch roi metadata while the stage is in flight.
    const int s0 = off_g[b];
    const int s1 = off_g[b + 1];
    const int i0 = s0 + (int)threadIdx.x;
    int hr0 = 0, wr0 = 0;
    if (i0 < s1) {
        hr0 = hTab[i0 * 7 + ph];
        wr0 = wTab[i0 * 7 + pw];
    }

    __syncthreads();   // drains vmcnt + barrier

    const float4* __restrict__ p4 = (const float4*)plane;

    // Process one roi given its packed ranges.
    auto process = [&](int i, int hr, int wr) {
        int hs = hr & 0xFF, he = hr >> 8;
        int ws = wr & 0xFF, we = wr >> 8;

        int a0  = ws >> 2;
        int nch = (we > ws) ? (((we - 1) >> 2) - a0 + 1) : 0;   // 0..4
        int base = a0 * 4;

        // 0/1 masks for the up-to-4 float4 chunks covering [ws, we)
        float4 m0, m1, m2, m3;
        {
            int k;
            k = base;      m0.x = (k>=ws && k<we); k++; m0.y = (k>=ws && k<we); k++;
                           m0.z = (k>=ws && k<we); k++; m0.w = (k>=ws && k<we);
            k = base + 4;  m1.x = (k>=ws && k<we); k++; m1.y = (k>=ws && k<we); k++;
                           m1.z = (k>=ws && k<we); k++; m1.w = (k>=ws && k<we);
            k = base + 8;  m2.x = (k>=ws && k<we); k++; m2.y = (k>=ws && k<we); k++;
                           m2.z = (k>=ws && k<we); k++; m2.w = (k>=ws && k<we);
            k = base + 12; m3.x = (k>=ws && k<we); k++; m3.y = (k>=ws && k<we); k++;
                           m3.z = (k>=ws && k<we); k++; m3.w = (k>=ws && k<we);
        }

        float s = 0.0f;
        for (int h = hs; h < he; ++h) {
            const float4* rw = p4 + h * (PSW / 4) + a0;
            {
                float4 v = rw[0];
                s = fmaf(v.x, m0.x, s); s = fmaf(v.y, m0.y, s);
                s = fmaf(v.z, m0.z, s); s = fmaf(v.w, m0.w, s);
            }
            if (nch > 1) {
                float4 v = rw[1];
                s = fmaf(v.x, m1.x, s); s = fmaf(v.y, m1.y, s);
                s = fmaf(v.z, m1.z, s); s = fmaf(v.w, m1.w, s);
            }
            if (nch > 2) {
                float4 v = rw[2];
                s = fmaf(v.x, m2.x, s); s = fmaf(v.y, m2.y, s);
                s = fmaf(v.z, m2.z, s); s = fmaf(v.w, m2.w, s);
            }
            if (nch > 3) {
                float4 v = rw[3];
                s = fmaf(v.x, m3.x, s); s = fmaf(v.y, m3.y, s);
                s = fmaf(v.z, m3.z, s); s = fmaf(v.w, m3.w, s);
            }
        }

        int area = (he - hs) * (we - ws);
        outT[(size_t)c * NMAX + i] = (area > 0) ? s / (float)area : 0.0f;
    };

    if (i0 < s1) process(i0, hr0, wr0);
    for (int i = i0 + 256; i < s1; i += 256) {
        int hr = hTab[i * 7 + ph];
        int wr = wTab[i * 7 + pw];
        process(i, hr, wr);
    }
}

__global__ __launch_bounds__(256) void psroi_transpose(
    const float* __restrict__ outT,       // [C, NMAX]
    const int* __restrict__ list,         // slot -> n
    float* __restrict__ out)              // [N, C]
{
    __shared__ float tile[32][33];
    __shared__ int ntab[32];

    const int c0 = blockIdx.x * 32;
    const int s0 = blockIdx.y * 32;
    const int tid = threadIdx.x;

    if (tid < 32) ntab[tid] = list[s0 + tid];

    #pragma unroll
    for (int k = 0; k < 4; ++k) {
        int idx = tid + k * 256;
        int r = idx >> 5, s = idx & 31;
        int c = c0 + r;
        if (c < PSC) tile[r][s] = outT[(size_t)c * NMAX + s0 + s];
    }
    __syncthreads();

    #pragma unroll
    for (int k = 0; k < 4; ++k) {
        int idx = tid + k * 256;
        int j = idx >> 5, cc = idx & 31;
        int c = c0 + cc;
        if (c < PSC) out[(size_t)ntab[j] * PSC + c] = tile[cc][j];
    }
}

extern "C" void kernel_launch(void* const* d_in, const int* in_sizes, int n_in,
                              void* d_out, int out_size, void* d_ws, size_t ws_size,
                              hipStream_t stream) {
    const float* x    = (const float*)d_in[0];
    const float* rois = (const float*)d_in[1];
    float* out        = (float*)d_out;
    int N = in_sizes[1] / 5;   // 1024

    char* ws = (char*)d_ws;
    int*      off_g = (int*)(ws + WS_OFF);
    int*      list  = (int*)(ws + WS_LIST);
    uint16_t* hTab  = (uint16_t*)(ws + WS_HTAB);
    uint16_t* wTab  = (uint16_t*)(ws + WS_WTAB);
    float*    outT  = (float*)(ws + WS_OUTT);

    psroi_prep<<<1, 1024, 0, stream>>>(rois, N, off_g, list, hTab, wTab);
    psroi_main<<<PSB * PSC, 256, 0, stream>>>(x, outT, off_g, hTab, wTab);
    psroi_transpose<<<dim3((PSC + 31) / 32, NMAX / 32), 256, 0, stream>>>(
        outT, list, out);
}